// Round 6
// baseline (201.444 us; speedup 1.0000x reference)
//
#include <hip/hip_runtime.h>
#include <hip/hip_bf16.h>

using u16 = unsigned short;
typedef __attribute__((ext_vector_type(8))) short short8v;
typedef __attribute__((ext_vector_type(4))) float f32x4;

#define MFMA16(a, b, c) __builtin_amdgcn_mfma_f32_16x16x32_bf16((a), (b), (c), 0, 0, 0)

#define GLOAD16(g, l) __builtin_amdgcn_global_load_lds(                       \
    (const __attribute__((address_space(1))) void*)(const void*)(g),          \
    (__attribute__((address_space(3))) void*)(void*)(l), 16, 0, 0)

static __device__ __forceinline__ u16 f2bf(float x) {
  __hip_bfloat16 h = __float2bfloat16(x);
  return __builtin_bit_cast(u16, h);
}

// one launch for all three f32->bf16 casts
__global__ __launch_bounds__(256) void cast3_f32_bf16(const float* __restrict__ a, u16* __restrict__ da,
                                                      const float* __restrict__ b, u16* __restrict__ db,
                                                      const float* __restrict__ c, u16* __restrict__ dc) {
  int bid = blockIdx.x;
  const float* s; u16* d; int i;
  if (bid < 4096)      { s = a; d = da; i = bid; }
  else if (bid < 5120) { s = b; d = db; i = bid - 4096; }
  else                 { s = c; d = dc; i = bid - 5120; }
  int idx = (i * 256 + threadIdx.x) * 4;
  float4 v = *reinterpret_cast<const float4*>(s + idx);
  ushort4 o;
  o.x = f2bf(v.x); o.y = f2bf(v.y); o.z = f2bf(v.z); o.w = f2bf(v.w);
  *reinterpret_cast<ushort4*>(d + idx) = o;
}

// C[M,N] fp32 = A[M,K] bf16 @ Bt[N,K]^T.  BM=64 BN=128 BK=32, 4 waves (2x2).
// Depth-2 counted-vmcnt pipeline (T3+T4): 4 LDS buffers; iter t issues tile
// t+2 via global_load_lds, waits vmcnt(6) (3/0 on tail) BEFORE s_barrier so
// each wave's own staging is retired; tile-t loads stay in flight across 2
// iterations. ds_read -> lgkmcnt(0)+sched_barrier(0) -> MFMA (rule #18).
// Buffer reused 4 tiles later; reads of buf[t%4] complete before barrier(t+1),
// overwrite (tile t+4, issued iter t+2) is after barrier(t+1) -> race-free.
__global__ __launch_bounds__(256) void gemm_bt(const u16* __restrict__ A,
                                               const u16* __restrict__ Bt,
                                               float* __restrict__ C,
                                               int M, int N, int K) {
  __shared__ u16 As[4][64 * 32];
  __shared__ u16 Bs[4][128 * 32];
  unsigned flat = blockIdx.y * gridDim.x + blockIdx.x;
  unsigned nwg = gridDim.x * gridDim.y;
  unsigned swz = (flat & 7) * (nwg >> 3) + (flat >> 3);  // nwg % 8 == 0
  int bm = swz % gridDim.x, bn = swz / gridDim.x;
  int tid = threadIdx.x;
  int wid = tid >> 6, l = tid & 63, lr = l & 15, lg = l >> 4;
  int wr = wid >> 1, wc = wid & 1;

  // staging: per gload a wave covers 16 rows x 32 elems (lane l -> row l>>2,
  // 16B chunk l&3); LDS dest = wave-uniform base + lane*16B (linear).
  int srow = l >> 2, scol = (l & 3) * 8;
  const u16* Ag  = A  + (size_t)(bm * 64 + wid * 16 + srow) * K + scol;
  const u16* Bg0 = Bt + (size_t)(bn * 128 + wid * 32 + srow) * K + scol;
  const u16* Bg1 = Bg0 + (size_t)16 * K;

  f32x4 acc[2][4];
#pragma unroll
  for (int m = 0; m < 2; m++)
#pragma unroll
    for (int n = 0; n < 4; n++) acc[m][n] = (f32x4){0.f, 0.f, 0.f, 0.f};

  const int NT = K >> 5;  // 32 k-tiles

  // prologue: issue tiles 0 and 1 (6 loads/wave outstanding)
#pragma unroll
  for (int t = 0; t < 2; t++) {
    GLOAD16(Ag + t * 32, &As[t][wid * 512]);
    GLOAD16(Bg0 + t * 32, &Bs[t][wid * 1024]);
    GLOAD16(Bg1 + t * 32, &Bs[t][wid * 1024 + 512]);
  }

  for (int t = 0; t < NT; t++) {
    int cur = t & 3;
    if (t + 2 < NT) {  // issue tile t+2; stays in flight for ~2 iterations
      int nb = (t + 2) & 3;
      int ko = (t + 2) * 32;
      GLOAD16(Ag + ko, &As[nb][wid * 512]);
      GLOAD16(Bg0 + ko, &Bs[nb][wid * 1024]);
      GLOAD16(Bg1 + ko, &Bs[nb][wid * 1024 + 512]);
    }
    // retire own tile-t staging (counted: never drain to 0 mid-loop)
    if (t + 2 < NT)      asm volatile("s_waitcnt vmcnt(6)" ::: "memory");
    else if (t + 1 < NT) asm volatile("s_waitcnt vmcnt(3)" ::: "memory");
    else                 asm volatile("s_waitcnt vmcnt(0)" ::: "memory");
    __builtin_amdgcn_s_barrier();  // all waves' tile-t slices visible

    short8v af[2], bfr[4];
#pragma unroll
    for (int m = 0; m < 2; m++)
      af[m] = *reinterpret_cast<const short8v*>(&As[cur][(wr * 32 + m * 16 + lr) * 32 + lg * 8]);
#pragma unroll
    for (int n = 0; n < 4; n++)
      bfr[n] = *reinterpret_cast<const short8v*>(&Bs[cur][(wc * 64 + n * 16 + lr) * 32 + lg * 8]);
    asm volatile("s_waitcnt lgkmcnt(0)" ::: "memory");
    __builtin_amdgcn_sched_barrier(0);  // pin MFMAs below the wait (rule #18)
    __builtin_amdgcn_s_setprio(1);
#pragma unroll
    for (int m = 0; m < 2; m++)
#pragma unroll
      for (int n = 0; n < 4; n++) acc[m][n] = MFMA16(af[m], bfr[n], acc[m][n]);
    __builtin_amdgcn_s_setprio(0);
  }

#pragma unroll
  for (int m = 0; m < 2; m++)
#pragma unroll
    for (int n = 0; n < 4; n++)
#pragma unroll
      for (int r = 0; r < 4; r++) {
        int row = bm * 64 + wr * 32 + m * 16 + lg * 4 + r;
        int col = bn * 128 + wc * 64 + n * 16 + lr;
        C[(size_t)row * N + col] = acc[m][n][r];
      }
}

// fused rotary + rms_norm (+ output scale): one wave per (b,t,h) row of 64.
// src layout (B,T,H,D) fp32; dst layout (B,H,T,D) bf16.
__global__ __launch_bounds__(256) void rope_rms(const float* __restrict__ src,
                                                u16* __restrict__ dst,
                                                const float* __restrict__ cosp,
                                                const float* __restrict__ sinp,
                                                float scale) {
  int R = blockIdx.x * 4 + (threadIdx.x >> 6);  // R = (b*T + t)*H + h
  int l = threadIdx.x & 63;
  int h = R & 15;
  int bt = R >> 4;
  int t = bt & 2047, b = bt >> 11;

  float v = src[((size_t)R << 6) + l];
  float p = __shfl_xor(v, 32);
  float c = cosp[(t << 5) + (l & 31)];
  float s = sinp[(t << 5) + (l & 31)];
  float r = v * c + ((l < 32) ? p * s : -p * s);
  float sq = r * r;
  sq += __shfl_xor(sq, 32);
  sq += __shfl_xor(sq, 16);
  sq += __shfl_xor(sq, 8);
  sq += __shfl_xor(sq, 4);
  sq += __shfl_xor(sq, 2);
  sq += __shfl_xor(sq, 1);
  float inv = rsqrtf(sq * (1.0f / 64.0f) + 1.1920928955078125e-07f) * scale;
  dst[((((size_t)b * 16 + h) * 2048 + t) << 6) + l] = f2bf(r * inv);
}

// (BH,T,D) -> (BH,D,T) bf16 transpose in 64x64 tiles.
__global__ __launch_bounds__(256) void transpose_td(const u16* __restrict__ src,
                                                    u16* __restrict__ dst) {
  __shared__ u16 Ld[64][72];
  int t0 = blockIdx.x << 6, bh = blockIdx.y;
  int tid = threadIdx.x;
#pragma unroll
  for (int i = 0; i < 2; i++) {
    int c = tid + i * 256, tr = c >> 3, sg = c & 7;
    *reinterpret_cast<short8v*>(&Ld[tr][sg * 8]) =
        *reinterpret_cast<const short8v*>(src + ((size_t)bh * 2048 + t0 + tr) * 64 + sg * 8);
  }
  __syncthreads();
#pragma unroll
  for (int i = 0; i < 2; i++) {
    int c = tid + i * 256, dr = c >> 3, sg = c & 7;
    short8v v;
#pragma unroll
    for (int j = 0; j < 8; j++) v[j] = (short)Ld[sg * 8 + j][dr];
    *reinterpret_cast<short8v*>(dst + ((size_t)bh * 64 + dr) * 2048 + t0 + sg * 8) = v;
  }
}

// sliding-window flash attention. Q: (B,H,T,D) bf16 PRE-SCALED by 0.125*log2e;
// KV: (B,H,T,D); KVt: (B,H,D,T). O: (B,T,H*D) bf16. Softmax in exp2 domain.
// 1 block = (b,h, 64 q rows); 4 waves x 16 q rows. K=V (single kv tensor).
__global__ __launch_bounds__(256) void attn_swa(const u16* __restrict__ Q,
                                                const u16* __restrict__ KV,
                                                const u16* __restrict__ KVt,
                                                u16* __restrict__ O,
                                                const int* __restrict__ winp) {
  const int T = 2048;
  int bid = blockIdx.x;
  int bh = bid & 31;                 // spread bh across consecutive blocks
  int qi = 31 - (bid >> 5);          // heavy q-tiles dispatched first
  int q0 = qi << 6;
  int b = bh >> 4, h = bh & 15;
  int W = *winp;
  int tid = threadIdx.x;
  int wid = tid >> 6, l = tid & 63, lr = l & 15, lg = l >> 4;

  __shared__ u16 Kl[64][72];       // [key][d]
  __shared__ u16 Vt[64][72];       // [d][key]  (staged from KVt, b128 rows)
  __shared__ u16 Pl[4][16][72];    // per-wave P tile [q][key]

  const u16* Qb = Q + (((size_t)bh * T + q0 + wid * 16 + lr) << 6);
  short8v aq0 = *reinterpret_cast<const short8v*>(Qb + lg * 8);
  short8v aq1 = *reinterpret_cast<const short8v*>(Qb + 32 + lg * 8);

  const short one_bf = (short)0x3F80;
  short8v vones = {one_bf, one_bf, one_bf, one_bf, one_bf, one_bf, one_bf, one_bf};

  float m_run[4], l_run[4];
  f32x4 oacc[4];
#pragma unroll
  for (int r = 0; r < 4; r++) { m_run[r] = -1e30f; l_run[r] = 0.f; }
#pragma unroll
  for (int dt = 0; dt < 4; dt++) oacc[dt] = (f32x4){0.f, 0.f, 0.f, 0.f};

  int lo = q0 - W;
  if (lo < 0) lo = 0;
  lo &= ~63;

  const u16* KVbh  = KV + (((size_t)bh * T) << 6);
  const u16* KVtbh = KVt + ((size_t)bh << 6) * T;
  int r8 = tid >> 3, sg = tid & 7;   // staging: rows r8 and r8+32, col seg sg

  // T14: prefetch first tile into registers (issue early / LDS-write late)
  short8v vK0 = *reinterpret_cast<const short8v*>(KVbh + ((size_t)(lo + r8) << 6) + sg * 8);
  short8v vK1 = *reinterpret_cast<const short8v*>(KVbh + ((size_t)(lo + r8 + 32) << 6) + sg * 8);
  short8v vV0 = *reinterpret_cast<const short8v*>(KVtbh + (size_t)r8 * T + lo + sg * 8);
  short8v vV1 = *reinterpret_cast<const short8v*>(KVtbh + (size_t)(r8 + 32) * T + lo + sg * 8);

  for (int kt = lo; kt <= q0; kt += 64) {
    __syncthreads();                 // prev compute done reading LDS
    *reinterpret_cast<short8v*>(&Kl[r8][sg * 8]) = vK0;
    *reinterpret_cast<short8v*>(&Kl[r8 + 32][sg * 8]) = vK1;
    *reinterpret_cast<short8v*>(&Vt[r8][sg * 8]) = vV0;
    *reinterpret_cast<short8v*>(&Vt[r8 + 32][sg * 8]) = vV1;
    __syncthreads();                 // tile ready
    if (kt < q0) {                   // prefetch next tile under compute
      vK0 = *reinterpret_cast<const short8v*>(KVbh + ((size_t)(kt + 64 + r8) << 6) + sg * 8);
      vK1 = *reinterpret_cast<const short8v*>(KVbh + ((size_t)(kt + 64 + r8 + 32) << 6) + sg * 8);
      vV0 = *reinterpret_cast<const short8v*>(KVtbh + (size_t)r8 * T + kt + 64 + sg * 8);
      vV1 = *reinterpret_cast<const short8v*>(KVtbh + (size_t)(r8 + 32) * T + kt + 64 + sg * 8);
    }

    // S = Q K^T  (16q x 64keys per wave), already in exp2 domain (q pre-scaled)
    f32x4 s[4];
    __builtin_amdgcn_s_setprio(1);
#pragma unroll
    for (int nt = 0; nt < 4; nt++) {
      s[nt] = (f32x4){0.f, 0.f, 0.f, 0.f};
      short8v b0 = *reinterpret_cast<const short8v*>(&Kl[nt * 16 + lr][lg * 8]);
      s[nt] = MFMA16(aq0, b0, s[nt]);
      short8v b1 = *reinterpret_cast<const short8v*>(&Kl[nt * 16 + lr][32 + lg * 8]);
      s[nt] = MFMA16(aq1, b1, s[nt]);
    }
    __builtin_amdgcn_s_setprio(0);

    // masking needed only on the diagonal tile (causal) and the window-edge
    // tile; wave-uniform test.
    bool edge = (kt + 63 > q0 + wid * 16) || ((q0 - kt) + wid * 16 + 15 > W);

    float al4[4];
#pragma unroll
    for (int r = 0; r < 4; r++) {
      float sv[4], mt;
      if (edge) {
        int t = q0 + wid * 16 + lg * 4 + r;
        mt = -3e38f;
#pragma unroll
        for (int nt = 0; nt < 4; nt++) {
          int k = kt + nt * 16 + lr;
          float val = ((k <= t) && (t - k <= W)) ? s[nt][r] : -3e38f;
          sv[nt] = val;
          mt = fmaxf(mt, val);
        }
      } else {
#pragma unroll
        for (int nt = 0; nt < 4; nt++) sv[nt] = s[nt][r];
        mt = fmaxf(fmaxf(sv[0], sv[1]), fmaxf(sv[2], sv[3]));
      }
      mt = fmaxf(mt, __shfl_xor(mt, 1));
      mt = fmaxf(mt, __shfl_xor(mt, 2));
      mt = fmaxf(mt, __shfl_xor(mt, 4));
      mt = fmaxf(mt, __shfl_xor(mt, 8));
      float mn = fmaxf(m_run[r], mt);
      float al = exp2f(m_run[r] - mn);
      m_run[r] = mn;
      al4[r] = al;
#pragma unroll
      for (int nt = 0; nt < 4; nt++) {
        Pl[wid][lg * 4 + r][nt * 16 + lr] = f2bf(exp2f(sv[nt] - mn));
      }
#pragma unroll
      for (int dt = 0; dt < 4; dt++) oacc[dt][r] *= al;
    }

    // O += P V ; row-sum of P via ones-MFMA on the idle matrix pipe
    short8v ap0 = *reinterpret_cast<const short8v*>(&Pl[wid][lr][lg * 8]);
    short8v ap1 = *reinterpret_cast<const short8v*>(&Pl[wid][lr][32 + lg * 8]);
    f32x4 psum = (f32x4){0.f, 0.f, 0.f, 0.f};
    __builtin_amdgcn_s_setprio(1);
    psum = MFMA16(ap0, vones, psum);
    psum = MFMA16(ap1, vones, psum);
#pragma unroll
    for (int dt = 0; dt < 4; dt++) {
      short8v v0 = *reinterpret_cast<const short8v*>(&Vt[dt * 16 + lr][lg * 8]);
      oacc[dt] = MFMA16(ap0, v0, oacc[dt]);
      short8v v1 = *reinterpret_cast<const short8v*>(&Vt[dt * 16 + lr][32 + lg * 8]);
      oacc[dt] = MFMA16(ap1, v1, oacc[dt]);
    }
    __builtin_amdgcn_s_setprio(0);
#pragma unroll
    for (int r = 0; r < 4; r++) l_run[r] = l_run[r] * al4[r] + psum[r];
  }

  // epilogue: O (B,T,C) bf16
#pragma unroll
  for (int r = 0; r < 4; r++) {
    int t = q0 + wid * 16 + lg * 4 + r;
    float inv = 1.f / l_run[r];
#pragma unroll
    for (int dt = 0; dt < 4; dt++) {
      O[(((size_t)b * T + t) << 10) + (h << 6) + dt * 16 + lr] = f2bf(oacc[dt][r] * inv);
    }
  }
}

extern "C" void kernel_launch(void* const* d_in, const int* in_sizes, int n_in,
                              void* d_out, int out_size, void* d_ws, size_t ws_size,
                              hipStream_t stream) {
  (void)in_sizes; (void)n_in; (void)out_size; (void)ws_size;
  const float* x    = (const float*)d_in[0];
  const float* cosp = (const float*)d_in[1];
  const float* sinp = (const float*)d_in[2];
  const float* kvw  = (const float*)d_in[3];
  const float* pw   = (const float*)d_in[4];
  const int*   win  = (const int*)d_in[5];

  char* w = (char*)d_ws;
  u16*   xbf   = (u16*)(w);                        // 0-8MB: x bf16, then q (B,H,T,D)
  u16*   kvwbf = (u16*)(w + (8u << 20));           // 8-10MB
  u16*   pwbf  = (u16*)(w + (10u << 20));          // 10-12MB
  float* kvf   = (float*)(w + (12u << 20));        // 12-28MB kv fp32 (dead after rope2)
  u16*   kvt   = (u16*)(w + (12u << 20));          // 12-20MB (over dead kvf)
  u16*   aout  = (u16*)(w + (20u << 20));          // 20-28MB (over dead kvf)
  u16*   kvbf  = (u16*)(w + (28u << 20));          // 28-36MB
  u16*   qbf   = xbf;

  cast3_f32_bf16<<<6144, 256, 0, stream>>>(x, xbf, kvw, kvwbf, pw, pwbf);

  // kv = x @ kv_w^T   (4096 x 1024 x 1024)
  gemm_bt<<<dim3(64, 8), 256, 0, stream>>>(xbf, kvwbf, kvf, 4096, 1024, 1024);

  // q = rmsnorm(rotary(x)) * 0.125*log2e;  kv = rmsnorm(rotary(kv))
  rope_rms<<<16384, 256, 0, stream>>>(x, qbf, cosp, sinp, 0.18033688011112042f);
  rope_rms<<<16384, 256, 0, stream>>>(kvf, kvbf, cosp, sinp, 1.0f);

  // kvt (B,H,D,T) for the PV B-operand
  transpose_td<<<dim3(32, 32), 256, 0, stream>>>(kvbf, kvt);

  // sliding-window attention -> (B,T,C) bf16
  attn_swa<<<1024, 256, 0, stream>>>(qbf, kvbf, kvt, aout, win);

  // out = attn_out @ proj_w^T -> fp32
  gemm_bt<<<dim3(64, 8), 256, 0, stream>>>(aout, pwbf, (float*)d_out, 4096, 1024, 1024);
}

// Round 7
// 180.838 us; speedup vs baseline: 1.1140x; 1.1140x over previous
//
#include <hip/hip_runtime.h>
#include <hip/hip_bf16.h>

using u16 = unsigned short;
typedef __attribute__((ext_vector_type(8))) short short8v;
typedef __attribute__((ext_vector_type(4))) float f32x4;

#define MFMA16(a, b, c) __builtin_amdgcn_mfma_f32_16x16x32_bf16((a), (b), (c), 0, 0, 0)

#define GLOAD16(g, l) __builtin_amdgcn_global_load_lds(                       \
    (const __attribute__((address_space(1))) void*)(const void*)(g),          \
    (__attribute__((address_space(3))) void*)(void*)(l), 16, 0, 0)

static __device__ __forceinline__ u16 f2bf(float x) {
  __hip_bfloat16 h = __float2bfloat16(x);
  return __builtin_bit_cast(u16, h);
}

// one launch for all three f32->bf16 casts
__global__ __launch_bounds__(256) void cast3_f32_bf16(const float* __restrict__ a, u16* __restrict__ da,
                                                      const float* __restrict__ b, u16* __restrict__ db,
                                                      const float* __restrict__ c, u16* __restrict__ dc) {
  int bid = blockIdx.x;
  const float* s; u16* d; int i;
  if (bid < 4096)      { s = a; d = da; i = bid; }
  else if (bid < 5120) { s = b; d = db; i = bid - 4096; }
  else                 { s = c; d = dc; i = bid - 5120; }
  int idx = (i * 256 + threadIdx.x) * 4;
  float4 v = *reinterpret_cast<const float4*>(s + idx);
  ushort4 o;
  o.x = f2bf(v.x); o.y = f2bf(v.y); o.z = f2bf(v.z); o.w = f2bf(v.w);
  *reinterpret_cast<ushort4*>(d + idx) = o;
}

// C[M,N] fp32 = A[M,K] bf16 @ Bt[N,K]^T.  BM=64 BN=128 BK=32, 4 waves (2x2).
// Depth-2 counted-vmcnt pipeline (T3+T4), 4 LDS buffers (unchanged from r6).
__global__ __launch_bounds__(256) void gemm_bt(const u16* __restrict__ A,
                                               const u16* __restrict__ Bt,
                                               float* __restrict__ C,
                                               int M, int N, int K) {
  __shared__ u16 As[4][64 * 32];
  __shared__ u16 Bs[4][128 * 32];
  unsigned flat = blockIdx.y * gridDim.x + blockIdx.x;
  unsigned nwg = gridDim.x * gridDim.y;
  unsigned swz = (flat & 7) * (nwg >> 3) + (flat >> 3);  // nwg % 8 == 0
  int bm = swz % gridDim.x, bn = swz / gridDim.x;
  int tid = threadIdx.x;
  int wid = tid >> 6, l = tid & 63, lr = l & 15, lg = l >> 4;
  int wr = wid >> 1, wc = wid & 1;

  int srow = l >> 2, scol = (l & 3) * 8;
  const u16* Ag  = A  + (size_t)(bm * 64 + wid * 16 + srow) * K + scol;
  const u16* Bg0 = Bt + (size_t)(bn * 128 + wid * 32 + srow) * K + scol;
  const u16* Bg1 = Bg0 + (size_t)16 * K;

  f32x4 acc[2][4];
#pragma unroll
  for (int m = 0; m < 2; m++)
#pragma unroll
    for (int n = 0; n < 4; n++) acc[m][n] = (f32x4){0.f, 0.f, 0.f, 0.f};

  const int NT = K >> 5;

#pragma unroll
  for (int t = 0; t < 2; t++) {
    GLOAD16(Ag + t * 32, &As[t][wid * 512]);
    GLOAD16(Bg0 + t * 32, &Bs[t][wid * 1024]);
    GLOAD16(Bg1 + t * 32, &Bs[t][wid * 1024 + 512]);
  }

  for (int t = 0; t < NT; t++) {
    int cur = t & 3;
    if (t + 2 < NT) {
      int nb = (t + 2) & 3;
      int ko = (t + 2) * 32;
      GLOAD16(Ag + ko, &As[nb][wid * 512]);
      GLOAD16(Bg0 + ko, &Bs[nb][wid * 1024]);
      GLOAD16(Bg1 + ko, &Bs[nb][wid * 1024 + 512]);
    }
    if (t + 2 < NT)      asm volatile("s_waitcnt vmcnt(6)" ::: "memory");
    else if (t + 1 < NT) asm volatile("s_waitcnt vmcnt(3)" ::: "memory");
    else                 asm volatile("s_waitcnt vmcnt(0)" ::: "memory");
    __builtin_amdgcn_s_barrier();

    short8v af[2], bfr[4];
#pragma unroll
    for (int m = 0; m < 2; m++)
      af[m] = *reinterpret_cast<const short8v*>(&As[cur][(wr * 32 + m * 16 + lr) * 32 + lg * 8]);
#pragma unroll
    for (int n = 0; n < 4; n++)
      bfr[n] = *reinterpret_cast<const short8v*>(&Bs[cur][(wc * 64 + n * 16 + lr) * 32 + lg * 8]);
    asm volatile("s_waitcnt lgkmcnt(0)" ::: "memory");
    __builtin_amdgcn_sched_barrier(0);  // pin MFMAs below the wait (rule #18)
    __builtin_amdgcn_s_setprio(1);
#pragma unroll
    for (int m = 0; m < 2; m++)
#pragma unroll
      for (int n = 0; n < 4; n++) acc[m][n] = MFMA16(af[m], bfr[n], acc[m][n]);
    __builtin_amdgcn_s_setprio(0);
  }

#pragma unroll
  for (int m = 0; m < 2; m++)
#pragma unroll
    for (int n = 0; n < 4; n++)
#pragma unroll
      for (int r = 0; r < 4; r++) {
        int row = bm * 64 + wr * 32 + m * 16 + lg * 4 + r;
        int col = bn * 128 + wc * 64 + n * 16 + lr;
        C[(size_t)row * N + col] = acc[m][n][r];
      }
}

// fused rotary + rms_norm for q: one wave per (b,t,h) row of 64.
// src layout (B,T,H,D) fp32; dst layout (B,H,T,D) bf16. Pre-scaled output.
__global__ __launch_bounds__(256) void rope_rms(const float* __restrict__ src,
                                                u16* __restrict__ dst,
                                                const float* __restrict__ cosp,
                                                const float* __restrict__ sinp,
                                                float scale) {
  int R = blockIdx.x * 4 + (threadIdx.x >> 6);  // R = (b*T + t)*H + h
  int l = threadIdx.x & 63;
  int h = R & 15;
  int bt = R >> 4;
  int t = bt & 2047, b = bt >> 11;

  float v = src[((size_t)R << 6) + l];
  float p = __shfl_xor(v, 32);
  float c = cosp[(t << 5) + (l & 31)];
  float s = sinp[(t << 5) + (l & 31)];
  float r = v * c + ((l < 32) ? p * s : -p * s);
  float sq = r * r;
  sq += __shfl_xor(sq, 32);
  sq += __shfl_xor(sq, 16);
  sq += __shfl_xor(sq, 8);
  sq += __shfl_xor(sq, 4);
  sq += __shfl_xor(sq, 2);
  sq += __shfl_xor(sq, 1);
  float inv = rsqrtf(sq * (1.0f / 64.0f) + 1.1920928955078125e-07f) * scale;
  dst[((((size_t)b * 16 + h) * 2048 + t) << 6) + l] = f2bf(r * inv);
}

// fused rotary + rms_norm for kv, writing BOTH (B,H,T,D) and transposed
// (B,H,D,T) layouts (replaces rope_rms + transpose_td for kv).
// grid (T/64, BH); block 256 = 4 waves; wave w handles t-rows w*16..w*16+15.
__global__ __launch_bounds__(256) void rope_rms_kv(const float* __restrict__ src,
                                                   u16* __restrict__ dst,
                                                   u16* __restrict__ dstT,
                                                   const float* __restrict__ cosp,
                                                   const float* __restrict__ sinp) {
  __shared__ u16 Ld[64][72];
  int t0 = blockIdx.x << 6;
  int bh = blockIdx.y;
  int b = bh >> 4, h = bh & 15;
  int tid = threadIdx.x;
  int w = tid >> 6, l = tid & 63;

  float cl, sl;
  for (int i = 0; i < 16; i++) {
    int tt = w * 16 + i;
    int t = t0 + tt;
    float v = src[((((size_t)b * 2048 + t) * 16 + h) << 6) + l];
    float p = __shfl_xor(v, 32);
    cl = cosp[(t << 5) + (l & 31)];
    sl = sinp[(t << 5) + (l & 31)];
    float r = v * cl + ((l < 32) ? p * sl : -p * sl);
    float sq = r * r;
    sq += __shfl_xor(sq, 32);
    sq += __shfl_xor(sq, 16);
    sq += __shfl_xor(sq, 8);
    sq += __shfl_xor(sq, 4);
    sq += __shfl_xor(sq, 2);
    sq += __shfl_xor(sq, 1);
    float inv = rsqrtf(sq * (1.0f / 64.0f) + 1.1920928955078125e-07f);
    u16 val = f2bf(r * inv);
    dst[(((size_t)bh * 2048 + t) << 6) + l] = val;
    Ld[tt][l] = val;  // row tt uniform per wave-iter, l*2B -> 2-way (free)
  }
  __syncthreads();
  // transposed write: same pattern as the old transpose_td second loop
#pragma unroll
  for (int i = 0; i < 2; i++) {
    int c = tid + i * 256, dr = c >> 3, sg = c & 7;
    short8v v;
#pragma unroll
    for (int j = 0; j < 8; j++) v[j] = (short)Ld[sg * 8 + j][dr];
    *reinterpret_cast<short8v*>(dstT + ((size_t)bh * 64 + dr) * 2048 + t0 + sg * 8) = v;
  }
}

// sliding-window flash attention. Q: (B,H,T,D) bf16 PRE-SCALED by 0.125*log2e;
// KV: (B,H,T,D); KVt: (B,H,D,T). O: (B,T,H*D) bf16.
// NO online max: |s| <= 11.6 (rms-normed rows), so p = exp2(s-12) <= 1 and the
// final division cancels the fixed offset -> numerically identical softmax.
// 1 block = (b,h, 64 q rows); 4 waves x 16 q rows. K=V (single kv tensor).
__global__ __launch_bounds__(256) void attn_swa(const u16* __restrict__ Q,
                                                const u16* __restrict__ KV,
                                                const u16* __restrict__ KVt,
                                                u16* __restrict__ O,
                                                const int* __restrict__ winp) {
  const int T = 2048;
  int bid = blockIdx.x;
  int bh = bid & 31;                 // spread bh across consecutive blocks
  int qi = 31 - (bid >> 5);          // heavy q-tiles dispatched first
  int q0 = qi << 6;
  int b = bh >> 4, h = bh & 15;
  int W = *winp;
  int tid = threadIdx.x;
  int wid = tid >> 6, l = tid & 63, lr = l & 15, lg = l >> 4;

  __shared__ u16 Kl[64][72];       // [key][d]
  __shared__ u16 Vt[64][72];       // [d][key]  (staged from KVt, b128 rows)
  __shared__ u16 Pl[4][16][72];    // per-wave P tile [q][key]

  const u16* Qb = Q + (((size_t)bh * T + q0 + wid * 16 + lr) << 6);
  short8v aq0 = *reinterpret_cast<const short8v*>(Qb + lg * 8);
  short8v aq1 = *reinterpret_cast<const short8v*>(Qb + 32 + lg * 8);

  const short one_bf = (short)0x3F80;
  short8v vones = {one_bf, one_bf, one_bf, one_bf, one_bf, one_bf, one_bf, one_bf};

  float l_run[4];
  f32x4 oacc[4];
#pragma unroll
  for (int r = 0; r < 4; r++) l_run[r] = 0.f;
#pragma unroll
  for (int dt = 0; dt < 4; dt++) oacc[dt] = (f32x4){0.f, 0.f, 0.f, 0.f};

  int lo = q0 - W;
  if (lo < 0) lo = 0;
  lo &= ~63;

  const u16* KVbh  = KV + (((size_t)bh * T) << 6);
  const u16* KVtbh = KVt + ((size_t)bh << 6) * T;
  int r8 = tid >> 3, sg = tid & 7;   // staging: rows r8 and r8+32, col seg sg

  // T14: prefetch first tile into registers (issue early / LDS-write late)
  short8v vK0 = *reinterpret_cast<const short8v*>(KVbh + ((size_t)(lo + r8) << 6) + sg * 8);
  short8v vK1 = *reinterpret_cast<const short8v*>(KVbh + ((size_t)(lo + r8 + 32) << 6) + sg * 8);
  short8v vV0 = *reinterpret_cast<const short8v*>(KVtbh + (size_t)r8 * T + lo + sg * 8);
  short8v vV1 = *reinterpret_cast<const short8v*>(KVtbh + (size_t)(r8 + 32) * T + lo + sg * 8);

  for (int kt = lo; kt <= q0; kt += 64) {
    __syncthreads();                 // prev compute done reading LDS
    *reinterpret_cast<short8v*>(&Kl[r8][sg * 8]) = vK0;
    *reinterpret_cast<short8v*>(&Kl[r8 + 32][sg * 8]) = vK1;
    *reinterpret_cast<short8v*>(&Vt[r8][sg * 8]) = vV0;
    *reinterpret_cast<short8v*>(&Vt[r8 + 32][sg * 8]) = vV1;
    __syncthreads();                 // tile ready
    if (kt < q0) {                   // prefetch next tile under compute
      vK0 = *reinterpret_cast<const short8v*>(KVbh + ((size_t)(kt + 64 + r8) << 6) + sg * 8);
      vK1 = *reinterpret_cast<const short8v*>(KVbh + ((size_t)(kt + 64 + r8 + 32) << 6) + sg * 8);
      vV0 = *reinterpret_cast<const short8v*>(KVtbh + (size_t)r8 * T + kt + 64 + sg * 8);
      vV1 = *reinterpret_cast<const short8v*>(KVtbh + (size_t)(r8 + 32) * T + kt + 64 + sg * 8);
    }

    // S = Q K^T  (16q x 64keys per wave), exp2 domain (q pre-scaled)
    f32x4 s[4];
#pragma unroll
    for (int nt = 0; nt < 4; nt++) {
      s[nt] = (f32x4){0.f, 0.f, 0.f, 0.f};
      short8v b0 = *reinterpret_cast<const short8v*>(&Kl[nt * 16 + lr][lg * 8]);
      s[nt] = MFMA16(aq0, b0, s[nt]);
      short8v b1 = *reinterpret_cast<const short8v*>(&Kl[nt * 16 + lr][32 + lg * 8]);
      s[nt] = MFMA16(aq1, b1, s[nt]);
    }

    // p = exp2(s - 12); masking only on diagonal/window-edge tiles.
    bool edge = (kt + 63 > q0 + wid * 16) || ((q0 - kt) + wid * 16 + 15 > W);
#pragma unroll
    for (int r = 0; r < 4; r++) {
      if (edge) {
        int t = q0 + wid * 16 + lg * 4 + r;
#pragma unroll
        for (int nt = 0; nt < 4; nt++) {
          int k = kt + nt * 16 + lr;
          float val = ((k <= t) && (t - k <= W)) ? s[nt][r] : -1e30f;
          Pl[wid][lg * 4 + r][nt * 16 + lr] = f2bf(exp2f(val - 12.f));
        }
      } else {
#pragma unroll
        for (int nt = 0; nt < 4; nt++)
          Pl[wid][lg * 4 + r][nt * 16 + lr] = f2bf(exp2f(s[nt][r] - 12.f));
      }
    }

    // O += P V ; row-sum of P via ones-MFMA on the matrix pipe
    short8v ap0 = *reinterpret_cast<const short8v*>(&Pl[wid][lr][lg * 8]);
    short8v ap1 = *reinterpret_cast<const short8v*>(&Pl[wid][lr][32 + lg * 8]);
    f32x4 psum = (f32x4){0.f, 0.f, 0.f, 0.f};
    psum = MFMA16(ap0, vones, psum);
    psum = MFMA16(ap1, vones, psum);
#pragma unroll
    for (int dt = 0; dt < 4; dt++) {
      short8v v0 = *reinterpret_cast<const short8v*>(&Vt[dt * 16 + lr][lg * 8]);
      oacc[dt] = MFMA16(ap0, v0, oacc[dt]);
      short8v v1 = *reinterpret_cast<const short8v*>(&Vt[dt * 16 + lr][32 + lg * 8]);
      oacc[dt] = MFMA16(ap1, v1, oacc[dt]);
    }
#pragma unroll
    for (int r = 0; r < 4; r++) l_run[r] += psum[r];
  }

  // epilogue: O (B,T,C) bf16
#pragma unroll
  for (int r = 0; r < 4; r++) {
    int t = q0 + wid * 16 + lg * 4 + r;
    float inv = 1.f / l_run[r];
#pragma unroll
    for (int dt = 0; dt < 4; dt++) {
      O[(((size_t)b * T + t) << 10) + (h << 6) + dt * 16 + lr] = f2bf(oacc[dt][r] * inv);
    }
  }
}

extern "C" void kernel_launch(void* const* d_in, const int* in_sizes, int n_in,
                              void* d_out, int out_size, void* d_ws, size_t ws_size,
                              hipStream_t stream) {
  (void)in_sizes; (void)n_in; (void)out_size; (void)ws_size;
  const float* x    = (const float*)d_in[0];
  const float* cosp = (const float*)d_in[1];
  const float* sinp = (const float*)d_in[2];
  const float* kvw  = (const float*)d_in[3];
  const float* pw   = (const float*)d_in[4];
  const int*   win  = (const int*)d_in[5];

  char* w = (char*)d_ws;
  u16*   xbf   = (u16*)(w);                        // 0-8MB: x bf16, then q (B,H,T,D)
  u16*   kvwbf = (u16*)(w + (8u << 20));           // 8-10MB
  u16*   pwbf  = (u16*)(w + (10u << 20));          // 10-12MB
  float* kvf   = (float*)(w + (12u << 20));        // 12-28MB kv fp32 (dead after rope_kv)
  u16*   kvt   = (u16*)(w + (12u << 20));          // 12-20MB (over dead kvf? NO - kvf live)
  u16*   aout  = (u16*)(w + (20u << 20));          // 20-28MB
  u16*   kvbf  = (u16*)(w + (28u << 20));          // 28-36MB
  u16*   qbf   = xbf;
  // NOTE: rope_rms_kv reads kvf while writing kvt -> kvt must NOT alias kvf.
  kvt = (u16*)(w + (36u << 20));                   // 36-44MB (safe, no alias)

  cast3_f32_bf16<<<6144, 256, 0, stream>>>(x, xbf, kvw, kvwbf, pw, pwbf);

  // kv = x @ kv_w^T   (4096 x 1024 x 1024)
  gemm_bt<<<dim3(64, 8), 256, 0, stream>>>(xbf, kvwbf, kvf, 4096, 1024, 1024);

  // q = rmsnorm(rotary(x)) * 0.125*log2e
  rope_rms<<<16384, 256, 0, stream>>>(x, qbf, cosp, sinp, 0.18033688011112042f);
  // kv = rmsnorm(rotary(kv)) -> both (B,H,T,D) and (B,H,D,T)
  rope_rms_kv<<<dim3(32, 32), 256, 0, stream>>>(kvf, kvbf, kvt, cosp, sinp);

  // sliding-window attention -> (B,T,C) bf16
  attn_swa<<<1024, 256, 0, stream>>>(qbf, kvbf, kvt, aout, win);

  // out = attn_out @ proj_w^T -> fp32
  gemm_bt<<<dim3(64, 8), 256, 0, stream>>>(aout, pwbf, (float*)d_out, 4096, 1024, 1024);
}